// Round 12
// baseline (288.799 us; speedup 1.0000x reference)
//
#include <hip/hip_runtime.h>

// Fused LSTM (B=4096, T=256, I=128, H=64) + projection (O=10).
// 512 WGs x 256 threads (4 waves), 2 WGs/CU (independent recurrences hide
// each other's stalls). WG owns 8 batch rows; 16-row MFMA tile packs TWO
// timesteps (row tr: batch=2*(tr>>2)+(tr&1), parity=(tr>>1)&1; both steps of
// a batch row share a lane -> c-state in-lane). h exchange via half-zeroed
// LDS tiles hA/hB + __syncthreads (R10-proven; raw lgkm-barrier fails here).
// R12 vs R10: x NEVER goes through LDS. All 4 waves need identical
// A-fragments, so each lane loads its x fragment directly global->regs
// (8x dwordx4 per window, issued ~1 window ahead; 4-wave redundancy is
// L1-resident). Kills the x-ring staging whose in-flight loads made every
// __syncthreads vmcnt(0) drain a ~500-cyc shared stall.
// log2e-prescaled weights; shared-rcp gate algebra (7 trans/(b,j)); clamps
// keep any anomaly finite.

typedef __attribute__((ext_vector_type(8))) short bf16x8;
typedef __attribute__((ext_vector_type(4))) float f32x4;

#define T_STEPS 256
#define L2E 1.44269504f

#define HA_OFF 0          // 2048B h tile A (rows 0,1 mod 4 valid, rest zero)
#define HB_OFF 2048       // 2048B h tile B (rows 2,3 mod 4 valid, rest zero)
#define HF_OFF 4096       // 2048B fp32 final h (8 rows x 64)
#define LDS_SZ 6144

__device__ __forceinline__ short f2bf(float f) {           // prologue only
    unsigned u = __float_as_uint(f);
    u += 0x7FFFu + ((u >> 16) & 1u);
    return (short)(u >> 16);
}
__device__ __forceinline__ unsigned cvt_pk(float lo, float hi) {
    unsigned r;
    asm("v_cvt_pk_bf16_f32 %0, %1, %2" : "=v"(r) : "v"(lo), "v"(hi));
    return r;
}
__device__ __forceinline__ float frcp(float x) { float r; asm("v_rcp_f32 %0, %1" : "=v"(r) : "v"(x)); return r; }
__device__ __forceinline__ float fexp2_raw(float x) { float r; asm("v_exp_f32 %0, %1" : "=v"(r) : "v"(x)); return r; }
__device__ __forceinline__ float fexp2c(float x) {
    return fexp2_raw(fminf(fmaxf(x, -40.0f), 40.0f));
}
__device__ __forceinline__ bf16x8 packfrag(f32x4 a, f32x4 b) {
    union { bf16x8 s; unsigned u[4]; } w;
    w.u[0] = cvt_pk(a[0], a[1]); w.u[1] = cvt_pk(a[2], a[3]);
    w.u[2] = cvt_pk(b[0], b[1]); w.u[3] = cvt_pk(b[2], b[3]);
    return w.s;
}

#define MF(A, Bf, C) (C) = __builtin_amdgcn_mfma_f32_16x16x32_bf16((A), (Bf), (C), 0, 0, 0)
#define SYNC __syncthreads();

__global__ __launch_bounds__(256, 2) void lstm_kernel(
    const float* __restrict__ x,
    const float* __restrict__ W_ih,
    const float* __restrict__ W_hh,
    const float* __restrict__ b_ih,
    const float* __restrict__ b_hh,
    const float* __restrict__ W_out,
    const float* __restrict__ b_out,
    float* __restrict__ out)
{
    __shared__ __align__(16) char smem[LDS_SZ];

    const int tid  = threadIdx.x;
    const int lane = tid & 63;
    const int q    = tid >> 6;
    const int l15  = lane & 15;
    const int l4   = lane >> 4;
    const int b0   = blockIdx.x * 8;

    // zero hA + hB (4KB = 256 threads x 16B); HF is fully written later.
    ((f32x4*)smem)[tid] = (f32x4){0.f, 0.f, 0.f, 0.f};

    // ---------------- weight fragments (exp2-prescaled) ----------------
    bf16x8 Bih[4][4];
    bf16x8 Bhh[4][2];
    f32x4  biasC[4];
#pragma unroll
    for (int nt = 0; nt < 4; ++nt) {
        const float scl = (nt == 2) ? (2.0f * L2E) : (-L2E);
        const int row = nt * 64 + q * 16 + l15;
#pragma unroll
        for (int ks = 0; ks < 4; ++ks) {
            const float* p = W_ih + row * 128 + ks * 32 + l4 * 8;
            f32x4 a = *(const f32x4*)p;
            f32x4 b = *(const f32x4*)(p + 4);
            bf16x8 wv;
#pragma unroll
            for (int j = 0; j < 4; ++j) { wv[j] = f2bf(a[j] * scl); wv[4 + j] = f2bf(b[j] * scl); }
            Bih[nt][ks] = wv;
        }
#pragma unroll
        for (int ks = 0; ks < 2; ++ks) {
            const float* p = W_hh + row * 64 + ks * 32 + l4 * 8;
            f32x4 a = *(const f32x4*)p;
            f32x4 b = *(const f32x4*)(p + 4);
            bf16x8 wv;
#pragma unroll
            for (int j = 0; j < 4; ++j) { wv[j] = f2bf(a[j] * scl); wv[4 + j] = f2bf(b[j] * scl); }
            Bhh[nt][ks] = wv;
        }
        const float bb = (b_ih[row] + b_hh[row]) * scl;
        biasC[nt] = (f32x4){bb, bb, bb, bb};
    }

    // ---------------- h-tile address maps (swizzled) ----------------
    const int jcol = q * 16 + l15;
    int hbA_wr[2], hbB_wr[2];
#pragma unroll
    for (int u = 0; u < 2; ++u) {
        const int trA = l4 * 4 + u;        // step-even row, batch 2*l4+u
        const int trB = trA + 2;           // step-odd row, same batch
        hbA_wr[u] = ((trA * 128 + jcol * 2) ^ ((trA & 7) << 4) ^ ((trA >> 3) << 5));
        hbB_wr[u] = ((trB * 128 + jcol * 2) ^ ((trB & 7) << 4) ^ ((trB >> 3) << 5));
    }
    int hb_rd[2];
#pragma unroll
    for (int ks = 0; ks < 2; ++ks)
        hb_rd[ks] = ((l15 * 128 + ks * 64 + l4 * 16) ^ ((l15 & 7) << 4) ^ ((l15 >> 3) << 5));

    // ---------------- x direct-from-global lane addressing ----------------
    // A-frag row = l15 = tile row -> batch bb, step parity pp; k = 32ks+8*l4+j
    const int bb = 2 * (l15 >> 2) + (l15 & 1);
    const int pp = (l15 >> 1) & 1;
    const float* xlane = x + (size_t)(b0 + bb) * (T_STEPS * 128) + l4 * 8;

    f32x4 XR[8];   // raw f32 x for the NEXT window's XGEMM
#define XLOAD(TE)                                                              \
    {                                                                          \
      int t_ = (TE) + pp; t_ = t_ > 255 ? 255 : t_;                            \
      const float* s_ = xlane + (size_t)t_ * 128;                              \
      XR[0] = *(const f32x4*)(s_);       XR[1] = *(const f32x4*)(s_ + 4);      \
      XR[2] = *(const f32x4*)(s_ + 32);  XR[3] = *(const f32x4*)(s_ + 36);     \
      XR[4] = *(const f32x4*)(s_ + 64);  XR[5] = *(const f32x4*)(s_ + 68);     \
      XR[6] = *(const f32x4*)(s_ + 96);  XR[7] = *(const f32x4*)(s_ + 100);    \
    }

#define XGEMM_R(ACC)                                                           \
    {                                                                          \
        bf16x8 G0 = packfrag(XR[0], XR[1]);                                    \
        bf16x8 G1 = packfrag(XR[2], XR[3]);                                    \
        bf16x8 G2 = packfrag(XR[4], XR[5]);                                    \
        bf16x8 G3 = packfrag(XR[6], XR[7]);                                    \
        ACC[0] = biasC[0]; ACC[1] = biasC[1];                                  \
        ACC[2] = biasC[2]; ACC[3] = biasC[3];                                  \
        MF(G0, Bih[0][0], ACC[0]); MF(G0, Bih[1][0], ACC[1]);                  \
        MF(G0, Bih[2][0], ACC[2]); MF(G0, Bih[3][0], ACC[3]);                  \
        MF(G1, Bih[0][1], ACC[0]); MF(G1, Bih[1][1], ACC[1]);                  \
        MF(G1, Bih[2][1], ACC[2]); MF(G1, Bih[3][1], ACC[3]);                  \
        MF(G2, Bih[0][2], ACC[0]); MF(G2, Bih[1][2], ACC[1]);                  \
        MF(G2, Bih[2][2], ACC[2]); MF(G2, Bih[3][2], ACC[3]);                  \
        MF(G3, Bih[0][3], ACC[0]); MF(G3, Bih[1][3], ACC[1]);                  \
        MF(G3, Bih[2][3], ACC[2]); MF(G3, Bih[3][3], ACC[3]);                  \
    }

    // ---------------- prologue ----------------
    float c[2]  = {0.f, 0.f};
    float hl[2] = {0.f, 0.f};
    f32x4 accA[4], accB[4];

    XLOAD(0);            // x(0,1)
    XGEMM_R(accA);       // accA = bias + gx(win 0)
    XLOAD(2);            // x(2,3) -> window 0's XGEMM(ANXT)

    SYNC;                // hA/hB zero visible; all waves aligned

#define ALGEBRA(EI, EF, EG, EO, U)                                             \
    {                                                                          \
      float u_  = 1.0f + (EI);                                                 \
      float v_  = (EG) + 1.0f;                                                 \
      float w_  = 1.0f + (EF);                                                 \
      float uv_ = u_ * v_;                                                     \
      float num = __builtin_fmaf(c[U], uv_, ((EG) - 1.0f) * w_);               \
      c[U] = fminf(fmaxf(num * frcp(uv_ * w_), -30.0f), 30.0f);                \
      float E2_ = fexp2c(c[U] * (2.0f * L2E));                                 \
      hl[U] = (E2_ - 1.0f) * frcp((E2_ + 1.0f) * (1.0f + (EO)));               \
    }

    // Window W = steps (2W, 2W+1).
#define WINDOW(W, ACUR, ANXT)                                                  \
  {                                                                            \
    char* hA = smem + HA_OFF;                                                  \
    char* hB = smem + HB_OFF;                                                  \
    bf16x8 Ah0 = *(const bf16x8*)(hA + hb_rd[0]);                              \
    bf16x8 Ah1 = *(const bf16x8*)(hA + hb_rd[1]);                              \
    MF(Ah0, Bhh[0][0], ACUR[0]); MF(Ah0, Bhh[1][0], ACUR[1]);                  \
    MF(Ah0, Bhh[2][0], ACUR[2]); MF(Ah0, Bhh[3][0], ACUR[3]);                  \
    MF(Ah1, Bhh[0][1], ACUR[0]); MF(Ah1, Bhh[1][1], ACUR[1]);                  \
    MF(Ah1, Bhh[2][1], ACUR[2]); MF(Ah1, Bhh[3][1], ACUR[3]);                  \
    float Ei0 = fexp2c(ACUR[0][0]), Ei1 = fexp2c(ACUR[0][1]);                  \
    float Ef0 = fexp2c(ACUR[1][0]), Ef1 = fexp2c(ACUR[1][1]);                  \
    float Eg0 = fexp2c(ACUR[2][0]), Eg1 = fexp2c(ACUR[2][1]);                  \
    float Eo0 = fexp2c(ACUR[3][0]), Eo1 = fexp2c(ACUR[3][1]);                  \
    XGEMM_R(ANXT);                       /* gx(2W+2, 2W+3), consumes XR */     \
    ALGEBRA(Ei0, Ef0, Eg0, Eo0, 0)                                             \
    ALGEBRA(Ei1, Ef1, Eg1, Eo1, 1)                                             \
    {                                                                          \
      unsigned wp = cvt_pk(hl[0], hl[1]);                                      \
      *(short*)(hB + hbB_wr[0]) = (short)wp;                                   \
      *(short*)(hB + hbB_wr[1]) = (short)(wp >> 16);                           \
    }                                                                          \
    SYNC;                                                                      \
    XLOAD(2 * (W) + 4);                  /* x for window W+1, ~1 win ahead */  \
    bf16x8 Bh0 = *(const bf16x8*)(hB + hb_rd[0]);                              \
    bf16x8 Bh1 = *(const bf16x8*)(hB + hb_rd[1]);                              \
    MF(Bh0, Bhh[0][0], ACUR[0]); MF(Bh0, Bhh[1][0], ACUR[1]);                  \
    MF(Bh0, Bhh[2][0], ACUR[2]); MF(Bh0, Bhh[3][0], ACUR[3]);                  \
    MF(Bh1, Bhh[0][1], ACUR[0]); MF(Bh1, Bhh[1][1], ACUR[1]);                  \
    MF(Bh1, Bhh[2][1], ACUR[2]); MF(Bh1, Bhh[3][1], ACUR[3]);                  \
    float Fi0 = fexp2c(ACUR[0][2]), Fi1 = fexp2c(ACUR[0][3]);                  \
    float Ff0 = fexp2c(ACUR[1][2]), Ff1 = fexp2c(ACUR[1][3]);                  \
    float Fg0 = fexp2c(ACUR[2][2]), Fg1 = fexp2c(ACUR[2][3]);                  \
    float Fo0 = fexp2c(ACUR[3][2]), Fo1 = fexp2c(ACUR[3][3]);                  \
    ALGEBRA(Fi0, Ff0, Fg0, Fo0, 0)                                             \
    ALGEBRA(Fi1, Ff1, Fg1, Fo1, 1)                                             \
    {                                                                          \
      unsigned wp = cvt_pk(hl[0], hl[1]);                                      \
      *(short*)(hA + hbA_wr[0]) = (short)wp;                                   \
      *(short*)(hA + hbA_wr[1]) = (short)(wp >> 16);                           \
    }                                                                          \
    SYNC;                                                                      \
  }

    for (int w = 0; w < 128; w += 2) {
        WINDOW(w,     accA, accB);
        WINDOW(w + 1, accB, accA);
    }
#undef WINDOW
#undef XGEMM_R
#undef XLOAD
#undef ALGEBRA

    // ---------------- epilogue: out = h_last @ W_out.T + b_out -------------
#pragma unroll
    for (int u = 0; u < 2; ++u) {
        const int b = 2 * l4 + u;
        *(float*)(smem + HF_OFF + (b * 64 + jcol) * 4) = hl[u];
    }
    SYNC;

    if (tid < 80) {
        const int b = tid / 10;
        const int o = tid - b * 10;
        const f32x4* hf = (const f32x4*)(smem + HF_OFF + b * 256);
        const f32x4* wr = (const f32x4*)(W_out + o * 64);
        float s = b_out[o];
#pragma unroll
        for (int j4 = 0; j4 < 16; ++j4) {
            f32x4 h4 = hf[j4];
            f32x4 w4 = wr[j4];
            s += h4[0] * w4[0] + h4[1] * w4[1] + h4[2] * w4[2] + h4[3] * w4[3];
        }
        out[(b0 + b) * 10 + o] = s;
    }
}

extern "C" void kernel_launch(void* const* d_in, const int* in_sizes, int n_in,
                              void* d_out, int out_size, void* d_ws, size_t ws_size,
                              hipStream_t stream) {
    const float* x     = (const float*)d_in[0];
    const float* W_ih  = (const float*)d_in[1];
    const float* W_hh  = (const float*)d_in[2];
    const float* b_ih  = (const float*)d_in[3];
    const float* b_hh  = (const float*)d_in[4];
    const float* W_out = (const float*)d_in[5];
    const float* b_out = (const float*)d_in[6];
    (void)in_sizes; (void)n_in; (void)out_size; (void)d_ws; (void)ws_size;

    lstm_kernel<<<dim3(512), dim3(256), 0, stream>>>(
        x, W_ih, W_hh, b_ih, b_hh, W_out, b_out, (float*)d_out);
}

// Round 14
// 163.767 us; speedup vs baseline: 1.7635x; 1.7635x over previous
//
#include <hip/hip_runtime.h>

// Fused LSTM (B=4096, T=256, I=128, H=64) + projection (O=10).
// FINAL (= R6, best proven: 163 µs, absmax 1.95e-3).
// 256 WGs x 256 threads (4 waves, 1/SIMD); wave q owns interleaved gate slice
// {64*nt + 16*q + col} so i/f/g/o for one (b,j) share a lane.
// 4-set rotating accumulators: window t finishes gates(t) in acc[t&3] via the
// 8 recurrent h-MFMAs; the 16 x-MFMAs build gx(t+2) in acc[(t+2)&3] and are
// issued between the nonlin trans levels so exp2/rcp latency overlaps MFMA +
// staging filler. log2e prescaled weights (i,f,o rows * -log2e; g rows *
// +2*log2e); shared-rcp gate algebra (7 trans per (b,j)). x staged via
// 4-deep LDS ring (bf16 A-frags); h via double-buffered swizzled LDS;
// raw lgkm-only barrier (vmcnt never drained -> 4-window x-prefetch slack).
//
// Session record: 320 (R1) -> 178 (fast trans + pipeline) -> 166 (shared-rcp
// algebra) -> 163 (acc rotation). All 2-streams-per-SIMD structures explored
// and rejected: redundant-MFMA (R4 +33%), producer/consumer (R3 +63%),
// 2-WG __syncthreads (R10 +12%, R12 +77% -- per-barrier vmcnt drain), dual
// recurrence with raw barrier (R7/8/11/13 -- data corruption, unexplained
// after 4 audits). Plateau = exposed single-stream recurrence chain at
// 1 wave/SIMD: ~650 cyc issue + ~880 cyc chain = 1530 cyc/step.

typedef __attribute__((ext_vector_type(8))) short bf16x8;
typedef __attribute__((ext_vector_type(4))) float f32x4;
typedef __attribute__((ext_vector_type(2))) unsigned u32x2;

#define T_STEPS 256
#define L2E 1.44269504f

#define XF_OFF 0          // 4 x 4096B bf16 x-frag ring
#define H_OFF  16384      // 2 x 2048B bf16 h double buffer
#define HF_OFF 20480      // 4096B fp32 final h
#define LDS_SZ 24576

__device__ __forceinline__ short f2bf(float f) {           // prologue only
    unsigned u = __float_as_uint(f);
    u += 0x7FFFu + ((u >> 16) & 1u);
    return (short)(u >> 16);
}
__device__ __forceinline__ unsigned cvt_pk(float lo, float hi) {
    unsigned r;
    asm("v_cvt_pk_bf16_f32 %0, %1, %2" : "=v"(r) : "v"(lo), "v"(hi));
    return r;
}
__device__ __forceinline__ float frcp(float x) { float r; asm("v_rcp_f32 %0, %1" : "=v"(r) : "v"(x)); return r; }
__device__ __forceinline__ float fexp2(float x) { float r; asm("v_exp_f32 %0, %1" : "=v"(r) : "v"(x)); return r; }

#define MF(A, Bf, C) (C) = __builtin_amdgcn_mfma_f32_16x16x32_bf16((A), (Bf), (C), 0, 0, 0)
#define SYNC { asm volatile("s_waitcnt lgkmcnt(0)" ::: "memory"); __builtin_amdgcn_s_barrier(); }

__global__ __launch_bounds__(256, 1) void lstm_kernel(
    const float* __restrict__ x,
    const float* __restrict__ W_ih,
    const float* __restrict__ W_hh,
    const float* __restrict__ b_ih,
    const float* __restrict__ b_hh,
    const float* __restrict__ W_out,
    const float* __restrict__ b_out,
    float* __restrict__ out)
{
    __shared__ __align__(16) char smem[LDS_SZ];

    const int tid  = threadIdx.x;
    const int lane = tid & 63;
    const int q    = tid >> 6;
    const int l15  = lane & 15;
    const int l4   = lane >> 4;
    const int b0   = blockIdx.x * 16;

    // ---------------- weight fragments (exp2-prescaled) ----------------
    // nt 0(i),1(f),3(o): * -L2E  (sigmoid via exp2); nt 2(g): * +2*L2E (tanh)
    bf16x8 Bih[4][4];
    bf16x8 Bhh[4][2];
    f32x4  biasC[4];
#pragma unroll
    for (int nt = 0; nt < 4; ++nt) {
        const float scl = (nt == 2) ? (2.0f * L2E) : (-L2E);
        const int row = nt * 64 + q * 16 + l15;
#pragma unroll
        for (int ks = 0; ks < 4; ++ks) {
            const float* p = W_ih + row * 128 + ks * 32 + l4 * 8;
            f32x4 a = *(const f32x4*)p;
            f32x4 b = *(const f32x4*)(p + 4);
            bf16x8 wv;
#pragma unroll
            for (int j = 0; j < 4; ++j) { wv[j] = f2bf(a[j] * scl); wv[4 + j] = f2bf(b[j] * scl); }
            Bih[nt][ks] = wv;
        }
#pragma unroll
        for (int ks = 0; ks < 2; ++ks) {
            const float* p = W_hh + row * 64 + ks * 32 + l4 * 8;
            f32x4 a = *(const f32x4*)p;
            f32x4 b = *(const f32x4*)(p + 4);
            bf16x8 wv;
#pragma unroll
            for (int j = 0; j < 4; ++j) { wv[j] = f2bf(a[j] * scl); wv[4 + j] = f2bf(b[j] * scl); }
            Bhh[nt][ks] = wv;
        }
        const float bb = (b_ih[row] + b_hh[row]) * scl;
        biasC[nt] = (f32x4){bb, bb, bb, bb};
    }

    // ---------------- address maps ----------------
    int xf_rd[4];
#pragma unroll
    for (int ks = 0; ks < 4; ++ks)
        xf_rd[ks] = (((ks * 64 + lane) * 16) ^ ((ks & 3) << 6));

    const int jcol = q * 16 + l15;
    int hb_wr[4];
#pragma unroll
    for (int r = 0; r < 4; ++r) {
        const int b = l4 * 4 + r;
        hb_wr[r] = ((b * 128 + jcol * 2) ^ ((b & 7) << 4) ^ ((b >> 3) << 5));
    }
    int hb_rd[2];
#pragma unroll
    for (int ks = 0; ks < 2; ++ks)
        hb_rd[ks] = ((l15 * 128 + ks * 64 + l4 * 16) ^ ((l15 & 7) << 4) ^ ((l15 >> 3) << 5));

    // x staging: thread loads one f32x4 per step (32 threads cover a 512B row
    // contiguously; 2 passes cover 16 rows), writes 8B bf16 at the frag slot.
    const int srow = tid >> 5;
    const int scc  = tid & 31;
    const int sks  = scc >> 3;
    const int sl4  = (scc & 7) >> 1;
    const int sh   = scc & 1;
    const int xf_wr0 = (((sks * 64 + sl4 * 16 + srow) * 16 + sh * 8) ^ ((sks & 3) << 6));
    const int xf_wr1 = (((sks * 64 + sl4 * 16 + srow + 8) * 16 + sh * 8) ^ ((sks & 3) << 6));
    const float* xsrc0 = x + (size_t)(b0 + srow) * (T_STEPS * 128) + scc * 4;
    const float* xsrc1 = x + (size_t)(b0 + srow + 8) * (T_STEPS * 128) + scc * 4;

    // ---------------- prologue ----------------
#pragma unroll
    for (int s = 0; s < 3; ++s) {
        f32x4 v0 = *(const f32x4*)(xsrc0 + (size_t)s * 128);
        f32x4 v1 = *(const f32x4*)(xsrc1 + (size_t)s * 128);
        u32x2 wv0; wv0.x = cvt_pk(v0[0], v0[1]); wv0.y = cvt_pk(v0[2], v0[3]);
        u32x2 wv1; wv1.x = cvt_pk(v1[0], v1[1]); wv1.y = cvt_pk(v1[2], v1[3]);
        *(u32x2*)(smem + XF_OFF + s * 4096 + xf_wr0) = wv0;
        *(u32x2*)(smem + XF_OFF + s * 4096 + xf_wr1) = wv1;
    }
    f32x4 P0[4], P1[4];
#pragma unroll
    for (int s = 0; s < 4; ++s) {
        P0[s] = *(const f32x4*)(xsrc0 + (size_t)(s + 3) * 128);
        P1[s] = *(const f32x4*)(xsrc1 + (size_t)(s + 3) * 128);
    }
    ((unsigned long long*)(smem + H_OFF + 2048))[tid] = 0ull;  // h(-1)=0 (buf 1)

    SYNC;

    float c[4]  = {0.f, 0.f, 0.f, 0.f};
    float hl[4] = {0.f, 0.f, 0.f, 0.f};

    f32x4 acc[4][4];                      // [set = t&3][gate]

#define XGEMM(SET, SLOT)                                                       \
    {                                                                          \
        const char* xfb_ = smem + XF_OFF + (SLOT) * 4096;                      \
        bf16x8 Ax0 = *(const bf16x8*)(xfb_ + xf_rd[0]);                        \
        bf16x8 Ax1 = *(const bf16x8*)(xfb_ + xf_rd[1]);                        \
        bf16x8 Ax2 = *(const bf16x8*)(xfb_ + xf_rd[2]);                        \
        bf16x8 Ax3 = *(const bf16x8*)(xfb_ + xf_rd[3]);                        \
        acc[SET][0] = biasC[0]; acc[SET][1] = biasC[1];                        \
        acc[SET][2] = biasC[2]; acc[SET][3] = biasC[3];                        \
        MF(Ax0, Bih[0][0], acc[SET][0]); MF(Ax0, Bih[1][0], acc[SET][1]);      \
        MF(Ax0, Bih[2][0], acc[SET][2]); MF(Ax0, Bih[3][0], acc[SET][3]);      \
        MF(Ax1, Bih[0][1], acc[SET][0]); MF(Ax1, Bih[1][1], acc[SET][1]);      \
        MF(Ax1, Bih[2][1], acc[SET][2]); MF(Ax1, Bih[3][1], acc[SET][3]);      \
        MF(Ax2, Bih[0][2], acc[SET][0]); MF(Ax2, Bih[1][2], acc[SET][1]);      \
        MF(Ax2, Bih[2][2], acc[SET][2]); MF(Ax2, Bih[3][2], acc[SET][3]);      \
        MF(Ax3, Bih[0][3], acc[SET][0]); MF(Ax3, Bih[1][3], acc[SET][1]);      \
        MF(Ax3, Bih[2][3], acc[SET][2]); MF(Ax3, Bih[3][3], acc[SET][3]);      \
    }

    XGEMM(0, 0);                          // acc[0] = bias + gx(0)
    XGEMM(1, 1);                          // acc[1] = bias + gx(1)

    // Window tt (T4 = tt&3): h-MFMA -> gates(tt) in acc[T4]; E-level trans;
    // x-MFMAs gx(tt+2) -> acc[(T4+2)&3] (latency filler); algebra+rcp; stage
    // x(tt+3); E2; reload P; rcp2; h-write; barrier.
#define WINDOW(tt, T4)                                                         \
  {                                                                            \
    const char* hbR = smem + H_OFF + ((((T4) & 1) ^ 1) * 2048);                \
    char*       hbW = smem + H_OFF + (((T4) & 1) * 2048);                      \
    char*       xfw = smem + XF_OFF + ((((T4) + 3) & 3) * 4096);               \
    bf16x8 Ah0 = *(const bf16x8*)(hbR + hb_rd[0]);                             \
    bf16x8 Ah1 = *(const bf16x8*)(hbR + hb_rd[1]);                             \
    MF(Ah0, Bhh[0][0], acc[T4][0]); MF(Ah0, Bhh[1][0], acc[T4][1]);            \
    MF(Ah0, Bhh[2][0], acc[T4][2]); MF(Ah0, Bhh[3][0], acc[T4][3]);            \
    MF(Ah1, Bhh[0][1], acc[T4][0]); MF(Ah1, Bhh[1][1], acc[T4][1]);            \
    MF(Ah1, Bhh[2][1], acc[T4][2]); MF(Ah1, Bhh[3][1], acc[T4][3]);            \
    float Ei[4], Ef[4], Eg[4], Eo[4], E2[4];                                   \
    _Pragma("unroll")                                                          \
    for (int r = 0; r < 4; ++r) {                                              \
      Ei[r] = fexp2(acc[T4][0][r]);                                            \
      Ef[r] = fexp2(acc[T4][1][r]);                                            \
      Eg[r] = fexp2(acc[T4][2][r]);                                            \
      Eo[r] = fexp2(acc[T4][3][r]);                                            \
    }                                                                          \
    XGEMM((((T4) + 2) & 3), (((T4) + 2) & 3));                                 \
    _Pragma("unroll")                                                          \
    for (int r = 0; r < 4; ++r) {                                              \
      float u  = 1.0f + Ei[r];                                                 \
      float v  = Eg[r] + 1.0f;                                                 \
      float w  = 1.0f + Ef[r];                                                 \
      float uv = u * v;                                                        \
      float num = __builtin_fmaf(c[r], uv, (Eg[r] - 1.0f) * w);                \
      c[r] = num * frcp(uv * w);                                               \
    }                                                                          \
    {                                                                          \
      u32x2 wv0; wv0.x = cvt_pk(P0[(T4)][0], P0[(T4)][1]);                     \
      wv0.y = cvt_pk(P0[(T4)][2], P0[(T4)][3]);                                \
      u32x2 wv1; wv1.x = cvt_pk(P1[(T4)][0], P1[(T4)][1]);                     \
      wv1.y = cvt_pk(P1[(T4)][2], P1[(T4)][3]);                                \
      *(u32x2*)(xfw + xf_wr0) = wv0;                                           \
      *(u32x2*)(xfw + xf_wr1) = wv1;                                           \
    }                                                                          \
    _Pragma("unroll")                                                          \
    for (int r = 0; r < 4; ++r)                                                \
      E2[r] = fexp2(c[r] * (2.0f * L2E));                                      \
    {                                                                          \
      const int tc = ((tt) + 7) & 255;                                         \
      P0[(T4)] = *(const f32x4*)(xsrc0 + (size_t)tc * 128);                    \
      P1[(T4)] = *(const f32x4*)(xsrc1 + (size_t)tc * 128);                    \
    }                                                                          \
    _Pragma("unroll")                                                          \
    for (int r = 0; r < 4; ++r)                                                \
      hl[r] = (E2[r] - 1.0f) * frcp((E2[r] + 1.0f) * (1.0f + Eo[r]));          \
    {                                                                          \
      unsigned w01 = cvt_pk(hl[0], hl[1]);                                     \
      unsigned w23 = cvt_pk(hl[2], hl[3]);                                     \
      *(short*)(hbW + hb_wr[0]) = (short)w01;                                  \
      *(short*)(hbW + hb_wr[1]) = (short)(w01 >> 16);                          \
      *(short*)(hbW + hb_wr[2]) = (short)w23;                                  \
      *(short*)(hbW + hb_wr[3]) = (short)(w23 >> 16);                          \
    }                                                                          \
    SYNC;                                                                      \
  }

    for (int t = 0; t < T_STEPS; t += 4) {
        WINDOW(t,     0);
        WINDOW(t + 1, 1);
        WINDOW(t + 2, 2);
        WINDOW(t + 3, 3);
    }
#undef WINDOW
#undef XGEMM

    // ---------------- epilogue: out = h_last @ W_out.T + b_out -------------
#pragma unroll
    for (int r = 0; r < 4; ++r) {
        const int b = l4 * 4 + r;
        *(float*)(smem + HF_OFF + (b * 64 + jcol) * 4) = hl[r];
    }
    SYNC;

    if (tid < 160) {
        const int b = tid / 10;
        const int o = tid - b * 10;
        const f32x4* hf = (const f32x4*)(smem + HF_OFF + b * 256);
        const f32x4* wr = (const f32x4*)(W_out + o * 64);
        float s = b_out[o];
#pragma unroll
        for (int j4 = 0; j4 < 16; ++j4) {
            f32x4 h4 = hf[j4];
            f32x4 w4 = wr[j4];
            s += h4[0] * w4[0] + h4[1] * w4[1] + h4[2] * w4[2] + h4[3] * w4[3];
        }
        out[(b0 + b) * 10 + o] = s;
    }
}

extern "C" void kernel_launch(void* const* d_in, const int* in_sizes, int n_in,
                              void* d_out, int out_size, void* d_ws, size_t ws_size,
                              hipStream_t stream) {
    const float* x     = (const float*)d_in[0];
    const float* W_ih  = (const float*)d_in[1];
    const float* W_hh  = (const float*)d_in[2];
    const float* b_ih  = (const float*)d_in[3];
    const float* b_hh  = (const float*)d_in[4];
    const float* W_out = (const float*)d_in[5];
    const float* b_out = (const float*)d_in[6];
    (void)in_sizes; (void)n_in; (void)out_size; (void)d_ws; (void)ws_size;

    lstm_kernel<<<dim3(256), dim3(256), 0, stream>>>(
        x, W_ih, W_hh, b_ih, b_hh, W_out, b_out, (float*)d_out);
}